// Round 6
// baseline (125.973 us; speedup 1.0000x reference)
//
#include <hip/hip_runtime.h>
#include <math.h>

// ---------------------------------------------------------------------------
// HyperMTANPro fused hypernetwork-MLP, MI355X (gfx950) — round 6.
//
// Single persistent mega-kernel, 256 blocks x 512 threads, manual grid
// barriers. Round 4 proved this structure correct but its barrier spun on an
// ACQUIRE load (cache-invalidate per poll -> 600us storm). Round-6 barrier:
//   arrive : fetch_add(1, RELEASE, AGENT)   (one wbL2 per block per phase)
//   spin   : fetch_add(0, RELAXED, AGENT) + s_sleep   (no invalidates)
// No acquire-invalidate is needed: every inter-phase buffer's data cache
// lines are first touched by readers only AFTER the producing phase (pad
// lines are separate 64B lines by construction), so no stale copies can
// exist within a launch; cross-replay staleness is cleared by the implicit
// kernel-launch invalidate. Weights stay L2-resident across phases.
//
// Refold: pbmm(x, hx@Wh+bh) + (hx@Wb+bb)  ==  [y (x) xa] @ Wfold
//   y = [hyper_x, 1] (H=11), xa = [x, 1, 0-pad] (NP mult of 32), k = h*NP+n.
// P0 packs weights to fp16 MFMA B-frag streaming order + g0 + pad cols.
// P1..P6: g1+L0 | L1 | L2 | L3*sig*g1 | LE | LL. Col-sliced task maps: the
// 8 waves of a block share one ct-slice of the blob (L1-hit B reuse).
// ---------------------------------------------------------------------------

typedef _Float16 f16x8 __attribute__((ext_vector_type(8)));
typedef float    f32x4 __attribute__((ext_vector_type(4)));

#define NBLK 256
#define NTHR 512
#define NTOT (NBLK * NTHR)     // 131072 threads

// blob half-offsets
#define OFF_G1 0
#define OFF_L0 73728
#define OFF_L1 479232
#define OFF_L2 704512
#define OFF_L3 929792
#define OFF_LE 1380352
#define OFF_LL 1583104
#define TOTAL_CHUNKS 200000    // 16B fragments; blob = 3.2 MB

// d_ws byte offsets
#define WS_XA0 3200000         // [1024][288] f16  g0 (+aug/pad)
#define WS_XG1 3789824         // [1024][256] f16  g1
#define WS_XL0 4314112         // [1024][160] f16  L0
#define WS_XL1 4641792         // [1024][160] f16  L1
#define WS_XL2 4969472         // [1024][160] f16  L2
#define WS_XA3 5297152         // [1024][288] f16  mask*g1
#define WS_XAE 5886976         // [1024][96]  f16  extractor
#define WS_BAR 6083584         // int barrier counter (memset 0 per launch)

// ---------------------------- weight prep (device fn) ----------------------

template<int N, int NP, int Mp, int M, int H>
__device__ __forceinline__ void prep_layer(int lci,
    const float* __restrict__ Wm, const float* __restrict__ bm,
    const float* __restrict__ Wb, const float* __restrict__ bb,
    _Float16* __restrict__ dst)
{
    constexpr int CT = Mp / 16;
    const int l  = lci & 63;
    const int sc = lci >> 6;
    const int c  = sc & (CT - 1);
    const int s  = sc / CT;
    const int col = c * 16 + (l & 15);
    const int k0  = s * 32 + ((l >> 4) << 3);
    const int h   = k0 / NP;
    const int n0  = k0 - h * NP;

    f16x8 v;
    #pragma unroll
    for (int i = 0; i < 8; ++i) {
        const int n = n0 + i;
        float w = 0.f;
        if (col < M && n <= N) {
            if (H == 11 && h < 10)
                w = (n < N) ? Wm[h * (N * M) + n * M + col] : Wb[h * M + col];
            else
                w = (n < N) ? bm[n * M + col] : bb[col];
        }
        v[i] = (_Float16)w;
    }
    *(f16x8*)(dst + (size_t)lci * 8) = v;
}

// ---------------------------- grid barrier ---------------------------------
// RELEASE arrival publishes this block's stores (wbL2); RELAXED RMW poll is
// coherent at the MALL with no cache-invalidate side effects.

__device__ __forceinline__ void grid_barrier(int* bar, int gen)
{
    __syncthreads();
    if (threadIdx.x == 0) {
        __hip_atomic_fetch_add(bar, 1, __ATOMIC_RELEASE, __HIP_MEMORY_SCOPE_AGENT);
        while (__hip_atomic_fetch_add(bar, 0, __ATOMIC_RELAXED, __HIP_MEMORY_SCOPE_AGENT)
               < gen * NBLK)
            __builtin_amdgcn_s_sleep(8);
    }
    __syncthreads();
}

// ---------------------------- layer wave -----------------------------------
// NR row-tiles (16 rows each) x 16 cols per wave; B-frag loaded once, used
// NR times. All loop indices compile-time (full unroll, no scratch).

template<int NR, int NPS, int H, int CT, bool SCALE, int STRIDE>
__device__ __forceinline__ void layer_waveN(
    const _Float16* __restrict__ Wl,    // layer blob base
    const _Float16* __restrict__ src,   // activation [1024][STRIDE]
    const float* __restrict__ hx,       // hyper_x [1024][10]
    int rb, int ct, int lane, f32x4* acc)
{
    const int r = lane & 15, q = lane >> 4;
    const int row0 = rb * (16 * NR) + r;

    f16x8 xv[NR][NPS];
    #pragma unroll
    for (int nr = 0; nr < NR; ++nr) {
        const _Float16* xp = src + (size_t)(row0 + nr * 16) * STRIDE + q * 8;
        #pragma unroll
        for (int j = 0; j < NPS; ++j) xv[nr][j] = *(const f16x8*)(xp + j * 32);
    }
    _Float16 ys[NR][H];
    if (SCALE) {
        #pragma unroll
        for (int nr = 0; nr < NR; ++nr)
            #pragma unroll
            for (int h = 0; h < H; ++h)
                ys[nr][h] = (h < 10) ? (_Float16)hx[(row0 + nr * 16) * 10 + h]
                                     : (_Float16)1.f;
    }
    f32x4 z = {0.f, 0.f, 0.f, 0.f};
    #pragma unroll
    for (int nr = 0; nr < NR; ++nr) acc[nr] = z;

    const _Float16* wbase = Wl + ((size_t)ct * 64 + lane) * 8;
    #pragma unroll
    for (int h = 0; h < H; ++h) {
        #pragma unroll
        for (int j = 0; j < NPS; ++j) {
            f16x8 b = *(const f16x8*)(wbase + (size_t)((h * NPS + j) * CT) * 512);
            #pragma unroll
            for (int nr = 0; nr < NR; ++nr) {
                f16x8 a = xv[nr][j];
                if (SCALE) {
                    const _Float16 s = ys[nr][h];
                    f16x8 y8 = {s, s, s, s, s, s, s, s};
                    a = a * y8;
                }
                acc[nr] = __builtin_amdgcn_mfma_f32_16x16x32_f16(a, b, acc[nr], 0, 0, 0);
            }
        }
    }
}

// ---------------------------- mega kernel ----------------------------------

__global__ __launch_bounds__(NTHR, 2) void mega_kernel(
    const float* __restrict__ hx,   const float* __restrict__ mlp_x,
    const float* __restrict__ G0w,  const float* __restrict__ G0b,
    const float* __restrict__ G1w,  const float* __restrict__ G1b,
    const float* __restrict__ Wmw0, const float* __restrict__ bmw0,
    const float* __restrict__ Wmb0, const float* __restrict__ bmb0,
    const float* __restrict__ Wmw1, const float* __restrict__ bmw1,
    const float* __restrict__ Wmb1, const float* __restrict__ bmb1,
    const float* __restrict__ Wmw2, const float* __restrict__ bmw2,
    const float* __restrict__ Wmb2, const float* __restrict__ bmb2,
    const float* __restrict__ Wmw3, const float* __restrict__ bmw3,
    const float* __restrict__ Wmb3, const float* __restrict__ bmb3,
    const float* __restrict__ Wew,  const float* __restrict__ bew,
    const float* __restrict__ Web,  const float* __restrict__ beb,
    const float* __restrict__ Wlw,  const float* __restrict__ blw,
    const float* __restrict__ Wlb,  const float* __restrict__ blb,
    char* __restrict__ ws, float* __restrict__ out)
{
    const int tid  = threadIdx.x;
    const int bid  = blockIdx.x;
    const int id   = bid * NTHR + tid;
    const int lane = tid & 63;
    const int gw   = bid * 8 + (tid >> 6);
    const int r = lane & 15, q = lane >> 4;

    _Float16* Wp  = (_Float16*)ws;
    _Float16* xa0 = (_Float16*)(ws + WS_XA0);
    _Float16* xg1 = (_Float16*)(ws + WS_XG1);
    _Float16* xl0 = (_Float16*)(ws + WS_XL0);
    _Float16* xl1 = (_Float16*)(ws + WS_XL1);
    _Float16* xl2 = (_Float16*)(ws + WS_XL2);
    _Float16* xa3 = (_Float16*)(ws + WS_XA3);
    _Float16* xae = (_Float16*)(ws + WS_XAE);
    int* bar = (int*)(ws + WS_BAR);

    // ---------------- P0: weight prep + g0 + pad init ----------------------
    for (int ci = id; ci < TOTAL_CHUNKS; ci += NTOT) {
        if (ci < 9216)
            prep_layer<256,288,256,256, 1>(ci,          nullptr, G1w, nullptr, G1b, Wp + OFF_G1);
        else if (ci < 59904)
            prep_layer<256,288,128,128,11>(ci - 9216,   Wmw0, bmw0, Wmb0, bmb0, Wp + OFF_L0);
        else if (ci < 88064)
            prep_layer<128,160,128,128,11>(ci - 59904,  Wmw1, bmw1, Wmb1, bmb1, Wp + OFF_L1);
        else if (ci < 116224)
            prep_layer<128,160,128,128,11>(ci - 88064,  Wmw2, bmw2, Wmb2, bmb2, Wp + OFF_L2);
        else if (ci < 172544)
            prep_layer<128,160,256,256,11>(ci - 116224, Wmw3, bmw3, Wmb3, bmb3, Wp + OFF_L3);
        else if (ci < 197888)
            prep_layer<256,288, 64, 64,11>(ci - 172544, Wew,  bew,  Web,  beb,  Wp + OFF_LE);
        else
            prep_layer< 64, 96, 16,  8,11>(ci - 197888, Wlw,  blw,  Wlb,  blb,  Wp + OFF_LL);
    }
    // g0 = relu(mlp_x @ G0w + G0b) -> xa0
    #pragma unroll
    for (int half = 0; half < 2; ++half) {
        const int row = (id >> 8) + half * 512;
        const int col = id & 255;
        float acc = G0b[col];
        #pragma unroll
        for (int n = 0; n < 9; ++n)
            acc = fmaf(mlp_x[row * 9 + n], G0w[n * 256 + col], acc);
        xa0[(size_t)row * 288 + col] = (_Float16)fmaxf(acc, 0.f);
    }
    // pad columns: slot M = 1.0 (augment), rest 0
    if (id < 32768) {
        const int rr = id >> 5, o = id & 31;
        const _Float16 v = (o == 0) ? (_Float16)1.f : (_Float16)0.f;
        xa0[(size_t)rr * 288 + 256 + o] = v;
        xl0[(size_t)rr * 160 + 128 + o] = v;
        xl1[(size_t)rr * 160 + 128 + o] = v;
        xl2[(size_t)rr * 160 + 128 + o] = v;
        xa3[(size_t)rr * 288 + 256 + o] = v;
        xae[(size_t)rr * 96  +  64 + o] = v;
    }
    grid_barrier(bar, 1);

    // ---------------- P1: g1 (512 wave2 tasks) + L0 (256 wave2) ------------
    if (gw < 512) {
        const int ct = gw >> 5, rbg = gw & 31;
        f32x4 acc[2];
        layer_waveN<2, 9, 1, 16, false, 288>(Wp + OFF_G1, xa0, hx, rbg, ct, lane, acc);
        #pragma unroll
        for (int nr = 0; nr < 2; ++nr)
            #pragma unroll
            for (int t4 = 0; t4 < 4; ++t4)
                xg1[(size_t)(rbg * 32 + nr * 16 + q * 4 + t4) * 256 + ct * 16 + r] =
                    (_Float16)fmaxf(acc[nr][t4], 0.f);
    } else if (gw < 768) {
        const int t = gw - 512, ct = t >> 5, rbg = t & 31;
        f32x4 acc[2];
        layer_waveN<2, 9, 11, 8, true, 288>(Wp + OFF_L0, xa0, hx, rbg, ct, lane, acc);
        #pragma unroll
        for (int nr = 0; nr < 2; ++nr)
            #pragma unroll
            for (int t4 = 0; t4 < 4; ++t4)
                xl0[(size_t)(rbg * 32 + nr * 16 + q * 4 + t4) * 160 + ct * 16 + r] =
                    (_Float16)fmaxf(acc[nr][t4], 0.f);
    }
    grid_barrier(bar, 2);

    // ---------------- P2: L1 (512 wave1 tasks, 64 blocks) -------------------
    if (gw < 512) {
        const int ct = gw >> 6, rb = gw & 63;
        f32x4 acc[1];
        layer_waveN<1, 5, 11, 8, true, 160>(Wp + OFF_L1, xl0, hx, rb, ct, lane, acc);
        #pragma unroll
        for (int t4 = 0; t4 < 4; ++t4)
            xl1[(size_t)(rb * 16 + q * 4 + t4) * 160 + ct * 16 + r] =
                (_Float16)fmaxf(acc[0][t4], 0.f);
    }
    grid_barrier(bar, 3);

    // ---------------- P3: L2 (512 wave1 tasks) ------------------------------
    if (gw < 512) {
        const int ct = gw >> 6, rb = gw & 63;
        f32x4 acc[1];
        layer_waveN<1, 5, 11, 8, true, 160>(Wp + OFF_L2, xl1, hx, rb, ct, lane, acc);
        #pragma unroll
        for (int t4 = 0; t4 < 4; ++t4)
            xl2[(size_t)(rb * 16 + q * 4 + t4) * 160 + ct * 16 + r] =
                (_Float16)fmaxf(acc[0][t4], 0.f);
    }
    grid_barrier(bar, 4);

    // ---------------- P4: L3 mask (512 wave2): sigmoid(.)*g1 -> xa3 ---------
    if (gw < 512) {
        const int ct = gw >> 5, rbg = gw & 31;
        f32x4 acc[2];
        layer_waveN<2, 5, 11, 16, true, 160>(Wp + OFF_L3, xl2, hx, rbg, ct, lane, acc);
        #pragma unroll
        for (int nr = 0; nr < 2; ++nr)
            #pragma unroll
            for (int t4 = 0; t4 < 4; ++t4) {
                const int row = rbg * 32 + nr * 16 + q * 4 + t4;
                const int col = ct * 16 + r;
                float v = 1.f / (1.f + __expf(-acc[nr][t4]));
                v *= (float)xg1[(size_t)row * 256 + col];
                xa3[(size_t)row * 288 + col] = (_Float16)v;
            }
    }
    grid_barrier(bar, 5);

    // ---------------- P5: LE extractor (256 wave1 tasks) --------------------
    if (gw < 256) {
        const int ct = gw >> 6, rb = gw & 63;
        f32x4 acc[1];
        layer_waveN<1, 9, 11, 4, true, 288>(Wp + OFF_LE, xa3, hx, rb, ct, lane, acc);
        #pragma unroll
        for (int t4 = 0; t4 < 4; ++t4)
            xae[(size_t)(rb * 16 + q * 4 + t4) * 96 + ct * 16 + r] =
                (_Float16)fmaxf(acc[0][t4], 0.f);
    }
    grid_barrier(bar, 6);

    // ---------------- P6: LL last (64 wave1 tasks) -> out f32 ---------------
    if (gw < 64) {
        const int rb = gw;
        f32x4 acc[1];
        layer_waveN<1, 3, 11, 1, true, 96>(Wp + OFF_LL, xae, hx, rb, 0, lane, acc);
        if (r < 8) {
            #pragma unroll
            for (int t4 = 0; t4 < 4; ++t4)
                out[(size_t)(rb * 16 + q * 4 + t4) * 8 + r] = acc[0][t4];
        }
    }
}

// ---------------------------- launch ---------------------------------------

extern "C" void kernel_launch(void* const* d_in, const int* in_sizes, int n_in,
                              void* d_out, int out_size, void* d_ws, size_t ws_size,
                              hipStream_t stream)
{
    char* ws = (char*)d_ws;
    hipMemsetAsync(ws + WS_BAR, 0, 64, stream);   // barrier counter = 0

    mega_kernel<<<NBLK, NTHR, 0, stream>>>(
        (const float*)d_in[0],  (const float*)d_in[1],
        (const float*)d_in[2],  (const float*)d_in[3],
        (const float*)d_in[4],  (const float*)d_in[5],
        (const float*)d_in[6],  (const float*)d_in[7],  (const float*)d_in[8],  (const float*)d_in[9],
        (const float*)d_in[10], (const float*)d_in[11], (const float*)d_in[12], (const float*)d_in[13],
        (const float*)d_in[14], (const float*)d_in[15], (const float*)d_in[16], (const float*)d_in[17],
        (const float*)d_in[18], (const float*)d_in[19], (const float*)d_in[20], (const float*)d_in[21],
        (const float*)d_in[22], (const float*)d_in[23], (const float*)d_in[24], (const float*)d_in[25],
        (const float*)d_in[26], (const float*)d_in[27], (const float*)d_in[28], (const float*)d_in[29],
        ws, (float*)d_out);
}

// Round 7
// 99.144 us; speedup vs baseline: 1.2706x; 1.2706x over previous
//
#include <hip/hip_runtime.h>
#include <math.h>

// ---------------------------------------------------------------------------
// HyperMTANPro fused hypernetwork-MLP, MI355X (gfx950) — round 7.
//
// Single persistent mega-kernel, 256 blocks x 512 threads, manual grid
// barriers. Barrier history: r4 acquire-load poll -> invalidate storm (600us);
// r6 fetch_add(0) RMW poll -> MALL atomic-unit serialization (~18us/barrier).
// r7: tree arrival (16 group counters, 64B apart, release RMW; last-of-group
// promotes to root) + RELAXED agent LOAD poll (sc1: bypasses XCD-L2, served
// in parallel, no invalidates). Visibility: release-RMW wbL2-flushes each
// block's stores to MALL before its arrival is visible; readers first-touch
// the data lines (or hold own-XCD dirty latest), so no acquire-invalidate is
// needed; __syncthreads() orders the block's subsequent loads.
//
// Schedule (prep overlapped with compute):
//   P0: prep G1+L0 blobs + g0 + pad cols          | bar1
//   P1: L0 GEMM (blocks 0-63) || prep rest (64-255)| bar2
//   P2: L1 (blocks 0-63)                           | bar3
//   P3: L2 (blocks 0-63) || g1 (blocks 64-127)     | bar4
//   P4: L3 -> sigmoid * g1 (blocks 0-63)           | bar5
//   P5: LE (blocks 0-31)                           | bar6
//   P6: LL -> out (blocks 0-7)
//
// Refold: pbmm(x, hx@Wh+bh) + (hx@Wb+bb)  ==  [y (x) xa] @ Wfold
//   y = [hyper_x, 1] (H=11), xa = [x, 1, 0-pad] (NP mult of 32), k = h*NP+n.
// Blob = fp16 MFMA B-frag streaming order: frag(s,c) lane l elem i =
//   W'[k=s*32+(l>>4)*8+i][col=c*16+(l&15)]; 16B/lane contiguous.
// ---------------------------------------------------------------------------

typedef _Float16 f16x8 __attribute__((ext_vector_type(8)));
typedef float    f32x4 __attribute__((ext_vector_type(4)));

#define NBLK 256
#define NTHR 512
#define NTOT (NBLK * NTHR)     // 131072 threads

// blob half-offsets
#define OFF_G1 0
#define OFF_L0 73728
#define OFF_L1 479232
#define OFF_L2 704512
#define OFF_L3 929792
#define OFF_LE 1380352
#define OFF_LL 1583104
#define TOTAL_CHUNKS 200000    // 16B fragments; blob = 3.2 MB
#define CHUNKS_P0 59904        // G1 (9216) + L0 (50688) prepped in P0

// d_ws byte offsets
#define WS_XA0 3200000         // [1024][288] f16  g0 (+aug/pad)
#define WS_XG1 3789824         // [1024][256] f16  g1
#define WS_XL0 4314112         // [1024][160] f16  L0
#define WS_XL1 4641792         // [1024][160] f16  L1
#define WS_XL2 4969472         // [1024][160] f16  L2
#define WS_XA3 5297152         // [1024][288] f16  mask*g1
#define WS_XAE 5886976         // [1024][96]  f16  extractor
#define WS_BAR 6083584         // barrier: root int[16] + 16 group ctrs @64B

// ---------------------------- weight prep (device fn) ----------------------

template<int N, int NP, int Mp, int M, int H>
__device__ __forceinline__ void prep_layer(int lci,
    const float* __restrict__ Wm, const float* __restrict__ bm,
    const float* __restrict__ Wb, const float* __restrict__ bb,
    _Float16* __restrict__ dst)
{
    constexpr int CT = Mp / 16;
    const int l  = lci & 63;
    const int sc = lci >> 6;
    const int c  = sc & (CT - 1);
    const int s  = sc / CT;
    const int col = c * 16 + (l & 15);
    const int k0  = s * 32 + ((l >> 4) << 3);
    const int h   = k0 / NP;
    const int n0  = k0 - h * NP;

    f16x8 v;
    #pragma unroll
    for (int i = 0; i < 8; ++i) {
        const int n = n0 + i;
        float w = 0.f;
        if (col < M && n <= N) {
            if (H == 11 && h < 10)
                w = (n < N) ? Wm[h * (N * M) + n * M + col] : Wb[h * M + col];
            else
                w = (n < N) ? bm[n * M + col] : bb[col];
        }
        v[i] = (_Float16)w;
    }
    *(f16x8*)(dst + (size_t)lci * 8) = v;
}

// ---------------------------- grid barrier ---------------------------------
// Tree arrival: release RMW on this block's group counter (16 groups of 16,
// counters 64B apart -> parallel L2 slices); the 16th arriver promotes to
// root. Poll: RELAXED agent atomic LOAD (bypasses XCD-L2 to MALL, parallel
// service, no invalidates) + s_sleep.

__device__ __forceinline__ void grid_barrier(int* barbase, int gen)
{
    __syncthreads();
    if (threadIdx.x == 0) {
        int* root = barbase;
        int* grp  = barbase + 16 + ((blockIdx.x >> 4) << 4);
        const int old = __hip_atomic_fetch_add(grp, 1, __ATOMIC_RELEASE,
                                               __HIP_MEMORY_SCOPE_AGENT);
        if (old == gen * 16 - 1)
            __hip_atomic_fetch_add(root, 1, __ATOMIC_RELEASE,
                                   __HIP_MEMORY_SCOPE_AGENT);
        while (__hip_atomic_load(root, __ATOMIC_RELAXED,
                                 __HIP_MEMORY_SCOPE_AGENT) < gen * 16)
            __builtin_amdgcn_s_sleep(2);
    }
    __syncthreads();
}

// ---------------------------- layer wave -----------------------------------
// NR row-tiles (16 rows) x 16 cols per wave; B-frag loaded once, used NR
// times. All indices compile-time (full unroll).

template<int NR, int NPS, int H, int CT, bool SCALE, int STRIDE>
__device__ __forceinline__ void layer_waveN(
    const _Float16* __restrict__ Wl,    // layer blob base
    const _Float16* __restrict__ src,   // activation [1024][STRIDE]
    const float* __restrict__ hx,       // hyper_x [1024][10]
    int rb, int ct, int lane, f32x4* acc)
{
    const int r = lane & 15, q = lane >> 4;
    const int row0 = rb * (16 * NR) + r;

    f16x8 xv[NR][NPS];
    #pragma unroll
    for (int nr = 0; nr < NR; ++nr) {
        const _Float16* xp = src + (size_t)(row0 + nr * 16) * STRIDE + q * 8;
        #pragma unroll
        for (int j = 0; j < NPS; ++j) xv[nr][j] = *(const f16x8*)(xp + j * 32);
    }
    _Float16 ys[NR][H];
    if (SCALE) {
        #pragma unroll
        for (int nr = 0; nr < NR; ++nr)
            #pragma unroll
            for (int h = 0; h < H; ++h)
                ys[nr][h] = (h < 10) ? (_Float16)hx[(row0 + nr * 16) * 10 + h]
                                     : (_Float16)1.f;
    }
    f32x4 z = {0.f, 0.f, 0.f, 0.f};
    #pragma unroll
    for (int nr = 0; nr < NR; ++nr) acc[nr] = z;

    const _Float16* wbase = Wl + ((size_t)ct * 64 + lane) * 8;
    #pragma unroll
    for (int h = 0; h < H; ++h) {
        #pragma unroll
        for (int j = 0; j < NPS; ++j) {
            f16x8 b = *(const f16x8*)(wbase + (size_t)((h * NPS + j) * CT) * 512);
            #pragma unroll
            for (int nr = 0; nr < NR; ++nr) {
                f16x8 a = xv[nr][j];
                if (SCALE) {
                    const _Float16 s = ys[nr][h];
                    f16x8 y8 = {s, s, s, s, s, s, s, s};
                    a = a * y8;
                }
                acc[nr] = __builtin_amdgcn_mfma_f32_16x16x32_f16(a, b, acc[nr], 0, 0, 0);
            }
        }
    }
}

// ---------------------------- mega kernel ----------------------------------

__global__ __launch_bounds__(NTHR, 2) void mega_kernel(
    const float* __restrict__ hx,   const float* __restrict__ mlp_x,
    const float* __restrict__ G0w,  const float* __restrict__ G0b,
    const float* __restrict__ G1w,  const float* __restrict__ G1b,
    const float* __restrict__ Wmw0, const float* __restrict__ bmw0,
    const float* __restrict__ Wmb0, const float* __restrict__ bmb0,
    const float* __restrict__ Wmw1, const float* __restrict__ bmw1,
    const float* __restrict__ Wmb1, const float* __restrict__ bmb1,
    const float* __restrict__ Wmw2, const float* __restrict__ bmw2,
    const float* __restrict__ Wmb2, const float* __restrict__ bmb2,
    const float* __restrict__ Wmw3, const float* __restrict__ bmw3,
    const float* __restrict__ Wmb3, const float* __restrict__ bmb3,
    const float* __restrict__ Wew,  const float* __restrict__ bew,
    const float* __restrict__ Web,  const float* __restrict__ beb,
    const float* __restrict__ Wlw,  const float* __restrict__ blw,
    const float* __restrict__ Wlb,  const float* __restrict__ blb,
    char* __restrict__ ws, float* __restrict__ out)
{
    const int tid  = threadIdx.x;
    const int bid  = blockIdx.x;
    const int id   = bid * NTHR + tid;
    const int lane = tid & 63;
    const int gw   = bid * 8 + (tid >> 6);
    const int r = lane & 15, q = lane >> 4;

    _Float16* Wp  = (_Float16*)ws;
    _Float16* xa0 = (_Float16*)(ws + WS_XA0);
    _Float16* xg1 = (_Float16*)(ws + WS_XG1);
    _Float16* xl0 = (_Float16*)(ws + WS_XL0);
    _Float16* xl1 = (_Float16*)(ws + WS_XL1);
    _Float16* xl2 = (_Float16*)(ws + WS_XL2);
    _Float16* xa3 = (_Float16*)(ws + WS_XA3);
    _Float16* xae = (_Float16*)(ws + WS_XAE);
    int* bar = (int*)(ws + WS_BAR);

    // ---------------- P0: prep G1+L0 blobs + g0 + pad init -----------------
    if (id < CHUNKS_P0) {
        if (id < 9216)
            prep_layer<256,288,256,256, 1>(id,        nullptr, G1w, nullptr, G1b, Wp + OFF_G1);
        else
            prep_layer<256,288,128,128,11>(id - 9216, Wmw0, bmw0, Wmb0, bmb0, Wp + OFF_L0);
    }
    // g0 = relu(mlp_x @ G0w + G0b) -> xa0
    #pragma unroll
    for (int half = 0; half < 2; ++half) {
        const int row = (id >> 8) + half * 512;
        const int col = id & 255;
        float acc = G0b[col];
        #pragma unroll
        for (int n = 0; n < 9; ++n)
            acc = fmaf(mlp_x[row * 9 + n], G0w[n * 256 + col], acc);
        xa0[(size_t)row * 288 + col] = (_Float16)fmaxf(acc, 0.f);
    }
    // pad columns: slot M = 1.0 (augment), rest 0 (separate 64B lines)
    if (id < 32768) {
        const int rr = id >> 5, o = id & 31;
        const _Float16 v = (o == 0) ? (_Float16)1.f : (_Float16)0.f;
        xa0[(size_t)rr * 288 + 256 + o] = v;
        xl0[(size_t)rr * 160 + 128 + o] = v;
        xl1[(size_t)rr * 160 + 128 + o] = v;
        xl2[(size_t)rr * 160 + 128 + o] = v;
        xa3[(size_t)rr * 288 + 256 + o] = v;
        xae[(size_t)rr * 96  +  64 + o] = v;
    }
    grid_barrier(bar, 1);

    // ---------------- P1: L0 (blocks 0-63) || prep rest (64-255) -----------
    if (bid < 64) {
        const int ct = gw >> 6, rb = gw & 63;     // ct uniform per block
        f32x4 acc[1];
        layer_waveN<1, 9, 11, 8, true, 288>(Wp + OFF_L0, xa0, hx, rb, ct, lane, acc);
        #pragma unroll
        for (int t4 = 0; t4 < 4; ++t4)
            xl0[(size_t)(rb * 16 + q * 4 + t4) * 160 + ct * 16 + r] =
                (_Float16)fmaxf(acc[0][t4], 0.f);
    } else {
        const int pid = (bid - 64) * NTHR + tid;  // 0..98303
        for (int ci = CHUNKS_P0 + pid; ci < TOTAL_CHUNKS; ci += 98304) {
            if (ci < 88064)
                prep_layer<128,160,128,128,11>(ci - 59904,  Wmw1, bmw1, Wmb1, bmb1, Wp + OFF_L1);
            else if (ci < 116224)
                prep_layer<128,160,128,128,11>(ci - 88064,  Wmw2, bmw2, Wmb2, bmb2, Wp + OFF_L2);
            else if (ci < 172544)
                prep_layer<128,160,256,256,11>(ci - 116224, Wmw3, bmw3, Wmb3, bmb3, Wp + OFF_L3);
            else if (ci < 197888)
                prep_layer<256,288, 64, 64,11>(ci - 172544, Wew,  bew,  Web,  beb,  Wp + OFF_LE);
            else
                prep_layer< 64, 96, 16,  8,11>(ci - 197888, Wlw,  blw,  Wlb,  blb,  Wp + OFF_LL);
        }
    }
    grid_barrier(bar, 2);

    // ---------------- P2: L1 (blocks 0-63) ----------------------------------
    if (bid < 64) {
        const int ct = gw >> 6, rb = gw & 63;
        f32x4 acc[1];
        layer_waveN<1, 5, 11, 8, true, 160>(Wp + OFF_L1, xl0, hx, rb, ct, lane, acc);
        #pragma unroll
        for (int t4 = 0; t4 < 4; ++t4)
            xl1[(size_t)(rb * 16 + q * 4 + t4) * 160 + ct * 16 + r] =
                (_Float16)fmaxf(acc[0][t4], 0.f);
    }
    grid_barrier(bar, 3);

    // ---------------- P3: L2 (blocks 0-63) || g1 (blocks 64-127) ------------
    if (bid < 64) {
        const int ct = gw >> 6, rb = gw & 63;
        f32x4 acc[1];
        layer_waveN<1, 5, 11, 8, true, 160>(Wp + OFF_L2, xl1, hx, rb, ct, lane, acc);
        #pragma unroll
        for (int t4 = 0; t4 < 4; ++t4)
            xl2[(size_t)(rb * 16 + q * 4 + t4) * 160 + ct * 16 + r] =
                (_Float16)fmaxf(acc[0][t4], 0.f);
    } else if (bid < 128) {
        const int t = gw - 512, ct = t >> 5, rbg = t & 31;   // ct uniform/block
        f32x4 acc[2];
        layer_waveN<2, 9, 1, 16, false, 288>(Wp + OFF_G1, xa0, hx, rbg, ct, lane, acc);
        #pragma unroll
        for (int nr = 0; nr < 2; ++nr)
            #pragma unroll
            for (int t4 = 0; t4 < 4; ++t4)
                xg1[(size_t)(rbg * 32 + nr * 16 + q * 4 + t4) * 256 + ct * 16 + r] =
                    (_Float16)fmaxf(acc[nr][t4], 0.f);
    }
    grid_barrier(bar, 4);

    // ---------------- P4: L3 mask (blocks 0-63): sigmoid(.)*g1 -> xa3 -------
    if (bid < 64) {
        const int ct = gw >> 5, rbg = gw & 31;
        f32x4 acc[2];
        layer_waveN<2, 5, 11, 16, true, 160>(Wp + OFF_L3, xl2, hx, rbg, ct, lane, acc);
        #pragma unroll
        for (int nr = 0; nr < 2; ++nr)
            #pragma unroll
            for (int t4 = 0; t4 < 4; ++t4) {
                const int row = rbg * 32 + nr * 16 + q * 4 + t4;
                const int col = ct * 16 + r;
                float v = 1.f / (1.f + __expf(-acc[nr][t4]));
                v *= (float)xg1[(size_t)row * 256 + col];
                xa3[(size_t)row * 288 + col] = (_Float16)v;
            }
    }
    grid_barrier(bar, 5);

    // ---------------- P5: LE extractor (blocks 0-31) ------------------------
    if (bid < 32) {
        const int ct = gw >> 6, rb = gw & 63;
        f32x4 acc[1];
        layer_waveN<1, 9, 11, 4, true, 288>(Wp + OFF_LE, xa3, hx, rb, ct, lane, acc);
        #pragma unroll
        for (int t4 = 0; t4 < 4; ++t4)
            xae[(size_t)(rb * 16 + q * 4 + t4) * 96 + ct * 16 + r] =
                (_Float16)fmaxf(acc[0][t4], 0.f);
    }
    grid_barrier(bar, 6);

    // ---------------- P6: LL last (blocks 0-7) -> out f32 -------------------
    if (gw < 64) {
        const int rb = gw;
        f32x4 acc[1];
        layer_waveN<1, 3, 11, 1, true, 96>(Wp + OFF_LL, xae, hx, rb, 0, lane, acc);
        if (r < 8) {
            #pragma unroll
            for (int t4 = 0; t4 < 4; ++t4)
                out[(size_t)(rb * 16 + q * 4 + t4) * 8 + r] = acc[0][t4];
        }
    }
}

// ---------------------------- launch ---------------------------------------

extern "C" void kernel_launch(void* const* d_in, const int* in_sizes, int n_in,
                              void* d_out, int out_size, void* d_ws, size_t ws_size,
                              hipStream_t stream)
{
    char* ws = (char*)d_ws;
    hipMemsetAsync(ws + WS_BAR, 0, 1280, stream);   // root + 16 group counters

    mega_kernel<<<NBLK, NTHR, 0, stream>>>(
        (const float*)d_in[0],  (const float*)d_in[1],
        (const float*)d_in[2],  (const float*)d_in[3],
        (const float*)d_in[4],  (const float*)d_in[5],
        (const float*)d_in[6],  (const float*)d_in[7],  (const float*)d_in[8],  (const float*)d_in[9],
        (const float*)d_in[10], (const float*)d_in[11], (const float*)d_in[12], (const float*)d_in[13],
        (const float*)d_in[14], (const float*)d_in[15], (const float*)d_in[16], (const float*)d_in[17],
        (const float*)d_in[18], (const float*)d_in[19], (const float*)d_in[20], (const float*)d_in[21],
        (const float*)d_in[22], (const float*)d_in[23], (const float*)d_in[24], (const float*)d_in[25],
        (const float*)d_in[26], (const float*)d_in[27], (const float*)d_in[28], (const float*)d_in[29],
        ws, (float*)d_out);
}

// Round 9
// 73.706 us; speedup vs baseline: 1.7091x; 1.3451x over previous
//
#include <hip/hip_runtime.h>
#include <math.h>

// ---------------------------------------------------------------------------
// HyperMTANPro fused hypernetwork-MLP, MI355X (gfx950) — round 9.
//
// Single persistent mega-kernel, 256 blocks x 512 threads, manual grid
// barriers. Barrier/visibility history:
//   r4: acquire-load poll -> buffer_inv per poll (600us storm)
//   r6: fetch_add(0) RMW poll -> MALL RMW serialization (~18us/barrier)
//   r7: release tree-arrival + relaxed load poll -> wbL2 per arrival
//       (XCD-L2 writeback walks, ~13us/barrier)
//   r8: nontemporal stores + all-relaxed barrier -> FAILED 0.236: `nt` is a
//       replacement hint, line still allocates DIRTY in writer XCD L2; with
//       no wbL2 anywhere, cross-XCD readers got stale MALL data.
// r9: cross-phase stores are AGENT-SCOPE RELAXED ATOMIC STORES -> emit
// global_store sc1, acked at the MALL (true write-through; XCD L2s never
// dirty). Barrier all-relaxed tree (16 group ctrs 64B apart -> root), poll
// via relaxed agent LOAD. Ordering chain: __syncthreads drains vmcnt(0)
// (sc1 stores MALL-acked) -> group RMW -> (data-dep) root RMW -> poller load
// sees root -> reader first-touches data lines (pads are separate 64B lines)
// -> MALL serves fresh data. Reader path identical to r6/r7 (which passed).
//
// Schedule:
//   P0: prep G1+L0 blobs + g0 + pad cols           | bar1
//   P1: L0 GEMM (blocks 0-63) || prep rest (64-255)| bar2
//   P2: L1 (blocks 0-63)                           | bar3
//   P3: L2 (blocks 0-63) || g1 (blocks 64-127)     | bar4
//   P4: L3 -> sigmoid * g1 (blocks 0-63)           | bar5
//   P5: LE (blocks 0-31)                           | bar6
//   P6: LL -> out (blocks 0-7)
//
// Refold: pbmm(x, hx@Wh+bh) + (hx@Wb+bb)  ==  [y (x) xa] @ Wfold
//   y = [hyper_x, 1] (H=11), xa = [x, 1, 0-pad] (NP mult of 32), k = h*NP+n.
// Blob = fp16 MFMA B-frag streaming order: frag(s,c) lane l elem i =
//   W'[k=s*32+(l>>4)*8+i][col=c*16+(l&15)]; 16B/lane contiguous.
// ---------------------------------------------------------------------------

typedef _Float16 f16x8 __attribute__((ext_vector_type(8)));
typedef float    f32x4 __attribute__((ext_vector_type(4)));
typedef unsigned long long u64;

#define NBLK 256
#define NTHR 512
#define NTOT (NBLK * NTHR)     // 131072 threads

// blob half-offsets
#define OFF_G1 0
#define OFF_L0 73728
#define OFF_L1 479232
#define OFF_L2 704512
#define OFF_L3 929792
#define OFF_LE 1380352
#define OFF_LL 1583104
#define TOTAL_CHUNKS 200000    // 16B fragments; blob = 3.2 MB
#define CHUNKS_P0 59904        // G1 (9216) + L0 (50688) prepped in P0

// d_ws byte offsets
#define WS_XA0 3200000         // [1024][288] f16  g0 (+aug/pad)
#define WS_XG1 3789824         // [1024][256] f16  g1
#define WS_XL0 4314112         // [1024][160] f16  L0
#define WS_XL1 4641792         // [1024][160] f16  L1
#define WS_XL2 4969472         // [1024][160] f16  L2
#define WS_XA3 5297152         // [1024][288] f16  mask*g1
#define WS_XAE 5886976         // [1024][96]  f16  extractor
#define WS_BAR 6083584         // barrier: root int[16] + 16 group ctrs @64B

// ---- write-through (sc1) store helpers: agent-scope relaxed atomic stores --

__device__ __forceinline__ void st_h(_Float16* p, _Float16 v)
{
    unsigned short b = __builtin_bit_cast(unsigned short, v);
    __hip_atomic_store((unsigned short*)p, b, __ATOMIC_RELAXED,
                       __HIP_MEMORY_SCOPE_AGENT);
}

__device__ __forceinline__ void st_v8(_Float16* p, f16x8 v)   // p 16B-aligned
{
    union { f16x8 v; u64 u[2]; } cv; cv.v = v;
    u64* q = (u64*)p;
    __hip_atomic_store(q,     cv.u[0], __ATOMIC_RELAXED, __HIP_MEMORY_SCOPE_AGENT);
    __hip_atomic_store(q + 1, cv.u[1], __ATOMIC_RELAXED, __HIP_MEMORY_SCOPE_AGENT);
}

// ---------------------------- weight prep (device fn) ----------------------

template<int N, int NP, int Mp, int M, int H>
__device__ __forceinline__ void prep_layer(int lci,
    const float* __restrict__ Wm, const float* __restrict__ bm,
    const float* __restrict__ Wb, const float* __restrict__ bb,
    _Float16* __restrict__ dst)
{
    constexpr int CT = Mp / 16;
    const int l  = lci & 63;
    const int sc = lci >> 6;
    const int c  = sc & (CT - 1);
    const int s  = sc / CT;
    const int col = c * 16 + (l & 15);
    const int k0  = s * 32 + ((l >> 4) << 3);
    const int h   = k0 / NP;
    const int n0  = k0 - h * NP;

    f16x8 v;
    #pragma unroll
    for (int i = 0; i < 8; ++i) {
        const int n = n0 + i;
        float w = 0.f;
        if (col < M && n <= N) {
            if (H == 11 && h < 10)
                w = (n < N) ? Wm[h * (N * M) + n * M + col] : Wb[h * M + col];
            else
                w = (n < N) ? bm[n * M + col] : bb[col];
        }
        v[i] = (_Float16)w;
    }
    st_v8(dst + (size_t)lci * 8, v);
}

// ---------------------------- grid barrier ---------------------------------
// Tree arrival, ALL RELAXED: group RMW (16 groups of 16 blocks, counters 64B
// apart); 16th arriver promotes to root (data-dep ordered). Poll: relaxed
// agent LOAD (MALL-served, parallel, no cache maintenance).

__device__ __forceinline__ void grid_barrier(int* barbase, int gen)
{
    __syncthreads();                 // drains vmcnt(0): sc1 stores MALL-acked
    if (threadIdx.x == 0) {
        int* root = barbase;
        int* grp  = barbase + 16 + ((blockIdx.x >> 4) << 4);
        const int old = __hip_atomic_fetch_add(grp, 1, __ATOMIC_RELAXED,
                                               __HIP_MEMORY_SCOPE_AGENT);
        if (old == gen * 16 - 1)
            __hip_atomic_fetch_add(root, 1, __ATOMIC_RELAXED,
                                   __HIP_MEMORY_SCOPE_AGENT);
        while (__hip_atomic_load(root, __ATOMIC_RELAXED,
                                 __HIP_MEMORY_SCOPE_AGENT) < gen * 16)
            __builtin_amdgcn_s_sleep(1);
    }
    __syncthreads();
}

// ---------------------------- layer wave -----------------------------------
// NR row-tiles (16 rows) x 16 cols per wave; B-frag loaded once, used NR
// times. All indices compile-time (full unroll).

template<int NR, int NPS, int H, int CT, bool SCALE, int STRIDE>
__device__ __forceinline__ void layer_waveN(
    const _Float16* __restrict__ Wl,    // layer blob base
    const _Float16* __restrict__ src,   // activation [1024][STRIDE]
    const float* __restrict__ hx,       // hyper_x [1024][10]
    int rb, int ct, int lane, f32x4* acc)
{
    const int r = lane & 15, q = lane >> 4;
    const int row0 = rb * (16 * NR) + r;

    f16x8 xv[NR][NPS];
    #pragma unroll
    for (int nr = 0; nr < NR; ++nr) {
        const _Float16* xp = src + (size_t)(row0 + nr * 16) * STRIDE + q * 8;
        #pragma unroll
        for (int j = 0; j < NPS; ++j) xv[nr][j] = *(const f16x8*)(xp + j * 32);
    }
    _Float16 ys[NR][H];
    if (SCALE) {
        #pragma unroll
        for (int nr = 0; nr < NR; ++nr)
            #pragma unroll
            for (int h = 0; h < H; ++h)
                ys[nr][h] = (h < 10) ? (_Float16)hx[(row0 + nr * 16) * 10 + h]
                                     : (_Float16)1.f;
    }
    f32x4 z = {0.f, 0.f, 0.f, 0.f};
    #pragma unroll
    for (int nr = 0; nr < NR; ++nr) acc[nr] = z;

    const _Float16* wbase = Wl + ((size_t)ct * 64 + lane) * 8;
    #pragma unroll
    for (int h = 0; h < H; ++h) {
        #pragma unroll
        for (int j = 0; j < NPS; ++j) {
            f16x8 b = *(const f16x8*)(wbase + (size_t)((h * NPS + j) * CT) * 512);
            #pragma unroll
            for (int nr = 0; nr < NR; ++nr) {
                f16x8 a = xv[nr][j];
                if (SCALE) {
                    const _Float16 s = ys[nr][h];
                    f16x8 y8 = {s, s, s, s, s, s, s, s};
                    a = a * y8;
                }
                acc[nr] = __builtin_amdgcn_mfma_f32_16x16x32_f16(a, b, acc[nr], 0, 0, 0);
            }
        }
    }
}

// ---------------------------- mega kernel ----------------------------------

__global__ __launch_bounds__(NTHR, 2) void mega_kernel(
    const float* __restrict__ hx,   const float* __restrict__ mlp_x,
    const float* __restrict__ G0w,  const float* __restrict__ G0b,
    const float* __restrict__ G1w,  const float* __restrict__ G1b,
    const float* __restrict__ Wmw0, const float* __restrict__ bmw0,
    const float* __restrict__ Wmb0, const float* __restrict__ bmb0,
    const float* __restrict__ Wmw1, const float* __restrict__ bmw1,
    const float* __restrict__ Wmb1, const float* __restrict__ bmb1,
    const float* __restrict__ Wmw2, const float* __restrict__ bmw2,
    const float* __restrict__ Wmb2, const float* __restrict__ bmb2,
    const float* __restrict__ Wmw3, const float* __restrict__ bmw3,
    const float* __restrict__ Wmb3, const float* __restrict__ bmb3,
    const float* __restrict__ Wew,  const float* __restrict__ bew,
    const float* __restrict__ Web,  const float* __restrict__ beb,
    const float* __restrict__ Wlw,  const float* __restrict__ blw,
    const float* __restrict__ Wlb,  const float* __restrict__ blb,
    char* __restrict__ ws, float* __restrict__ out)
{
    const int tid  = threadIdx.x;
    const int bid  = blockIdx.x;
    const int id   = bid * NTHR + tid;
    const int lane = tid & 63;
    const int gw   = bid * 8 + (tid >> 6);
    const int r = lane & 15, q = lane >> 4;

    _Float16* Wp  = (_Float16*)ws;
    _Float16* xa0 = (_Float16*)(ws + WS_XA0);
    _Float16* xg1 = (_Float16*)(ws + WS_XG1);
    _Float16* xl0 = (_Float16*)(ws + WS_XL0);
    _Float16* xl1 = (_Float16*)(ws + WS_XL1);
    _Float16* xl2 = (_Float16*)(ws + WS_XL2);
    _Float16* xa3 = (_Float16*)(ws + WS_XA3);
    _Float16* xae = (_Float16*)(ws + WS_XAE);
    int* bar = (int*)(ws + WS_BAR);

    // ---------------- P0: prep G1+L0 blobs + g0 + pad init -----------------
    if (id < CHUNKS_P0) {
        if (id < 9216)
            prep_layer<256,288,256,256, 1>(id,        nullptr, G1w, nullptr, G1b, Wp + OFF_G1);
        else
            prep_layer<256,288,128,128,11>(id - 9216, Wmw0, bmw0, Wmb0, bmb0, Wp + OFF_L0);
    }
    // g0 = relu(mlp_x @ G0w + G0b) -> xa0
    #pragma unroll
    for (int half = 0; half < 2; ++half) {
        const int row = (id >> 8) + half * 512;
        const int col = id & 255;
        float acc = G0b[col];
        #pragma unroll
        for (int n = 0; n < 9; ++n)
            acc = fmaf(mlp_x[row * 9 + n], G0w[n * 256 + col], acc);
        st_h(&xa0[(size_t)row * 288 + col], (_Float16)fmaxf(acc, 0.f));
    }
    // pad columns: slot M = 1.0 (augment), rest 0 (separate 64B lines)
    if (id < 32768) {
        const int rr = id >> 5, o = id & 31;
        const _Float16 v = (o == 0) ? (_Float16)1.f : (_Float16)0.f;
        st_h(&xa0[(size_t)rr * 288 + 256 + o], v);
        st_h(&xl0[(size_t)rr * 160 + 128 + o], v);
        st_h(&xl1[(size_t)rr * 160 + 128 + o], v);
        st_h(&xl2[(size_t)rr * 160 + 128 + o], v);
        st_h(&xa3[(size_t)rr * 288 + 256 + o], v);
        st_h(&xae[(size_t)rr * 96  +  64 + o], v);
    }
    grid_barrier(bar, 1);

    // ---------------- P1: L0 (blocks 0-63) || prep rest (64-255) -----------
    if (bid < 64) {
        const int ct = gw >> 6, rb = gw & 63;     // ct uniform per block
        f32x4 acc[1];
        layer_waveN<1, 9, 11, 8, true, 288>(Wp + OFF_L0, xa0, hx, rb, ct, lane, acc);
        #pragma unroll
        for (int t4 = 0; t4 < 4; ++t4)
            st_h(&xl0[(size_t)(rb * 16 + q * 4 + t4) * 160 + ct * 16 + r],
                 (_Float16)fmaxf(acc[0][t4], 0.f));
    } else {
        const int pid = (bid - 64) * NTHR + tid;  // 0..98303
        for (int ci = CHUNKS_P0 + pid; ci < TOTAL_CHUNKS; ci += 98304) {
            if (ci < 88064)
                prep_layer<128,160,128,128,11>(ci - 59904,  Wmw1, bmw1, Wmb1, bmb1, Wp + OFF_L1);
            else if (ci < 116224)
                prep_layer<128,160,128,128,11>(ci - 88064,  Wmw2, bmw2, Wmb2, bmb2, Wp + OFF_L2);
            else if (ci < 172544)
                prep_layer<128,160,256,256,11>(ci - 116224, Wmw3, bmw3, Wmb3, bmb3, Wp + OFF_L3);
            else if (ci < 197888)
                prep_layer<256,288, 64, 64,11>(ci - 172544, Wew,  bew,  Web,  beb,  Wp + OFF_LE);
            else
                prep_layer< 64, 96, 16,  8,11>(ci - 197888, Wlw,  blw,  Wlb,  blb,  Wp + OFF_LL);
        }
    }
    grid_barrier(bar, 2);

    // ---------------- P2: L1 (blocks 0-63) ----------------------------------
    if (bid < 64) {
        const int ct = gw >> 6, rb = gw & 63;
        f32x4 acc[1];
        layer_waveN<1, 5, 11, 8, true, 160>(Wp + OFF_L1, xl0, hx, rb, ct, lane, acc);
        #pragma unroll
        for (int t4 = 0; t4 < 4; ++t4)
            st_h(&xl1[(size_t)(rb * 16 + q * 4 + t4) * 160 + ct * 16 + r],
                 (_Float16)fmaxf(acc[0][t4], 0.f));
    }
    grid_barrier(bar, 3);

    // ---------------- P3: L2 (blocks 0-63) || g1 (blocks 64-127) ------------
    if (bid < 64) {
        const int ct = gw >> 6, rb = gw & 63;
        f32x4 acc[1];
        layer_waveN<1, 5, 11, 8, true, 160>(Wp + OFF_L2, xl1, hx, rb, ct, lane, acc);
        #pragma unroll
        for (int t4 = 0; t4 < 4; ++t4)
            st_h(&xl2[(size_t)(rb * 16 + q * 4 + t4) * 160 + ct * 16 + r],
                 (_Float16)fmaxf(acc[0][t4], 0.f));
    } else if (bid < 128) {
        const int t = gw - 512, ct = t >> 5, rbg = t & 31;   // ct uniform/block
        f32x4 acc[2];
        layer_waveN<2, 9, 1, 16, false, 288>(Wp + OFF_G1, xa0, hx, rbg, ct, lane, acc);
        #pragma unroll
        for (int nr = 0; nr < 2; ++nr)
            #pragma unroll
            for (int t4 = 0; t4 < 4; ++t4)
                st_h(&xg1[(size_t)(rbg * 32 + nr * 16 + q * 4 + t4) * 256 + ct * 16 + r],
                     (_Float16)fmaxf(acc[nr][t4], 0.f));
    }
    grid_barrier(bar, 4);

    // ---------------- P4: L3 mask (blocks 0-63): sigmoid(.)*g1 -> xa3 -------
    if (bid < 64) {
        const int ct = gw >> 5, rbg = gw & 31;
        f32x4 acc[2];
        layer_waveN<2, 5, 11, 16, true, 160>(Wp + OFF_L3, xl2, hx, rbg, ct, lane, acc);
        #pragma unroll
        for (int nr = 0; nr < 2; ++nr)
            #pragma unroll
            for (int t4 = 0; t4 < 4; ++t4) {
                const int row = rbg * 32 + nr * 16 + q * 4 + t4;
                const int col = ct * 16 + r;
                float v = 1.f / (1.f + __expf(-acc[nr][t4]));
                v *= (float)xg1[(size_t)row * 256 + col];
                st_h(&xa3[(size_t)row * 288 + col], (_Float16)v);
            }
    }
    grid_barrier(bar, 5);

    // ---------------- P5: LE extractor (blocks 0-31) ------------------------
    if (bid < 32) {
        const int ct = gw >> 6, rb = gw & 63;
        f32x4 acc[1];
        layer_waveN<1, 9, 11, 4, true, 288>(Wp + OFF_LE, xa3, hx, rb, ct, lane, acc);
        #pragma unroll
        for (int t4 = 0; t4 < 4; ++t4)
            st_h(&xae[(size_t)(rb * 16 + q * 4 + t4) * 96 + ct * 16 + r],
                 (_Float16)fmaxf(acc[0][t4], 0.f));
    }
    grid_barrier(bar, 6);

    // ---------------- P6: LL last (blocks 0-7) -> out f32 -------------------
    if (gw < 64) {
        const int rb = gw;
        f32x4 acc[1];
        layer_waveN<1, 3, 11, 1, true, 96>(Wp + OFF_LL, xae, hx, rb, 0, lane, acc);
        if (r < 8) {
            #pragma unroll
            for (int t4 = 0; t4 < 4; ++t4)
                out[(size_t)(rb * 16 + q * 4 + t4) * 8 + r] = acc[0][t4];
        }
    }
}

// ---------------------------- launch ---------------------------------------

extern "C" void kernel_launch(void* const* d_in, const int* in_sizes, int n_in,
                              void* d_out, int out_size, void* d_ws, size_t ws_size,
                              hipStream_t stream)
{
    char* ws = (char*)d_ws;
    hipMemsetAsync(ws + WS_BAR, 0, 1280, stream);   // root + 16 group counters

    mega_kernel<<<NBLK, NTHR, 0, stream>>>(
        (const float*)d_in[0],  (const float*)d_in[1],
        (const float*)d_in[2],  (const float*)d_in[3],
        (const float*)d_in[4],  (const float*)d_in[5],
        (const float*)d_in[6],  (const float*)d_in[7],  (const float*)d_in[8],  (const float*)d_in[9],
        (const float*)d_in[10], (const float*)d_in[11], (const float*)d_in[12], (const float*)d_in[13],
        (const float*)d_in[14], (const float*)d_in[15], (const float*)d_in[16], (const float*)d_in[17],
        (const float*)d_in[18], (const float*)d_in[19], (const float*)d_in[20], (const float*)d_in[21],
        (const float*)d_in[22], (const float*)d_in[23], (const float*)d_in[24], (const float*)d_in[25],
        (const float*)d_in[26], (const float*)d_in[27], (const float*)d_in[28], (const float*)d_in[29],
        ws, (float*)d_out);
}

// Round 10
// 67.186 us; speedup vs baseline: 1.8750x; 1.0970x over previous
//
#include <hip/hip_runtime.h>
#include <math.h>

// ---------------------------------------------------------------------------
// HyperMTANPro fused hypernetwork-MLP, MI355X (gfx950) — round 10.
//
// Single persistent mega-kernel, 256 blocks x 512 threads, manual grid
// barriers (r9 recipe, proven correct): cross-phase stores are AGENT-scope
// relaxed atomic stores (global_store sc1, MALL-acked write-through; XCD L2s
// never dirty) + all-relaxed tree barrier (16 group ctrs 64B apart -> root;
// poll = relaxed agent load + s_sleep). r9 measured 70us with VGPR=64:
// phases were LATENCY-bound (shallow B-load scheduling vs ~500-700cy MALL
// latency). r10:
//   (1) layer_waveN streams B-frags through an explicit 2-deep x 8-frag
//       software pipeline (all indices compile-time) -> >=16 loads in flight.
//   (2) LE+LL fused in one phase via LDS staging (barrier count 6 -> 5).
//   (3) __launch_bounds__(512) -> 256-VGPR cap for the pipeline registers.
//
// Schedule:
//   P0: prep G1+L0 blobs + g0 + pad cols           | bar1
//   P1: L0 (blocks 0-63) || prep rest (64-255)     | bar2
//   P2: L1 (blocks 0-63)                           | bar3
//   P3: L2 (blocks 0-63) || g1 (blocks 64-127)     | bar4
//   P4: L3 -> sigmoid * g1 (blocks 0-63)           | bar5
//   P5: LE -> LDS -> LL -> out (blocks 0-31, block-local sync only)
//
// Refold: pbmm(x, hx@Wh+bh) + (hx@Wb+bb)  ==  [y (x) xa] @ Wfold
//   y = [hyper_x, 1] (H=11), xa = [x, 1, 0-pad] (NP mult of 32), k = h*NP+n.
// Blob = fp16 MFMA B-frag streaming order: frag(s,c) lane l elem i =
//   W'[k=s*32+(l>>4)*8+i][col=c*16+(l&15)]; 16B/lane contiguous.
// ---------------------------------------------------------------------------

typedef _Float16 f16x8 __attribute__((ext_vector_type(8)));
typedef float    f32x4 __attribute__((ext_vector_type(4)));
typedef unsigned long long u64;

#define NBLK 256
#define NTHR 512
#define NTOT (NBLK * NTHR)     // 131072 threads

// blob half-offsets
#define OFF_G1 0
#define OFF_L0 73728
#define OFF_L1 479232
#define OFF_L2 704512
#define OFF_L3 929792
#define OFF_LE 1380352
#define OFF_LL 1583104
#define TOTAL_CHUNKS 200000    // 16B fragments; blob = 3.2 MB
#define CHUNKS_P0 59904        // G1 (9216) + L0 (50688) prepped in P0

// d_ws byte offsets
#define WS_XA0 3200000         // [1024][288] f16  g0 (+aug/pad)
#define WS_XG1 3789824         // [1024][256] f16  g1
#define WS_XL0 4314112         // [1024][160] f16  L0
#define WS_XL1 4641792         // [1024][160] f16  L1
#define WS_XL2 4969472         // [1024][160] f16  L2
#define WS_XA3 5297152         // [1024][288] f16  mask*g1
#define WS_BAR 6083584         // barrier: root int[16] + 16 group ctrs @64B

// ---- write-through (sc1) store helpers: agent-scope relaxed atomic stores --

__device__ __forceinline__ void st_h(_Float16* p, _Float16 v)
{
    unsigned short b = __builtin_bit_cast(unsigned short, v);
    __hip_atomic_store((unsigned short*)p, b, __ATOMIC_RELAXED,
                       __HIP_MEMORY_SCOPE_AGENT);
}

__device__ __forceinline__ void st_v8(_Float16* p, f16x8 v)   // p 16B-aligned
{
    union { f16x8 v; u64 u[2]; } cv; cv.v = v;
    u64* q = (u64*)p;
    __hip_atomic_store(q,     cv.u[0], __ATOMIC_RELAXED, __HIP_MEMORY_SCOPE_AGENT);
    __hip_atomic_store(q + 1, cv.u[1], __ATOMIC_RELAXED, __HIP_MEMORY_SCOPE_AGENT);
}

// ---------------------------- weight prep (device fn) ----------------------

template<int N, int NP, int Mp, int M, int H>
__device__ __forceinline__ void prep_layer(int lci,
    const float* __restrict__ Wm, const float* __restrict__ bm,
    const float* __restrict__ Wb, const float* __restrict__ bb,
    _Float16* __restrict__ dst)
{
    constexpr int CT = Mp / 16;
    const int l  = lci & 63;
    const int sc = lci >> 6;
    const int c  = sc & (CT - 1);
    const int s  = sc / CT;
    const int col = c * 16 + (l & 15);
    const int k0  = s * 32 + ((l >> 4) << 3);
    const int h   = k0 / NP;
    const int n0  = k0 - h * NP;

    f16x8 v;
    #pragma unroll
    for (int i = 0; i < 8; ++i) {
        const int n = n0 + i;
        float w = 0.f;
        if (col < M && n <= N) {
            if (H == 11 && h < 10)
                w = (n < N) ? Wm[h * (N * M) + n * M + col] : Wb[h * M + col];
            else
                w = (n < N) ? bm[n * M + col] : bb[col];
        }
        v[i] = (_Float16)w;
    }
    st_v8(dst + (size_t)lci * 8, v);
}

// ---------------------------- grid barrier ---------------------------------

__device__ __forceinline__ void grid_barrier(int* barbase, int gen)
{
    __syncthreads();                 // drains vmcnt(0): sc1 stores MALL-acked
    if (threadIdx.x == 0) {
        int* root = barbase;
        int* grp  = barbase + 16 + ((blockIdx.x >> 4) << 4);
        const int old = __hip_atomic_fetch_add(grp, 1, __ATOMIC_RELAXED,
                                               __HIP_MEMORY_SCOPE_AGENT);
        if (old == gen * 16 - 1)
            __hip_atomic_fetch_add(root, 1, __ATOMIC_RELAXED,
                                   __HIP_MEMORY_SCOPE_AGENT);
        while (__hip_atomic_load(root, __ATOMIC_RELAXED,
                                 __HIP_MEMORY_SCOPE_AGENT) < gen * 16)
            __builtin_amdgcn_s_sleep(1);
    }
    __syncthreads();
}

// ---------------------------- layer wave -----------------------------------
// NR row-tiles (16 rows) x 16 cols per wave. B-frags stream through an
// explicit 2-deep x 8-frag pipeline (>=16 loads in flight); all array
// indices are compile-time under full unroll (no scratch).
// src0 = activation pointer pre-offset to the row block (row r=0);
// grow0 = global row index of that row block (for hx scales).

template<int NR, int NPS, int H, int CT, bool SCALE, int STRIDE>
__device__ __forceinline__ void layer_waveN(
    const _Float16* __restrict__ Wl,
    const _Float16* __restrict__ src0,
    const float* __restrict__ hx,
    int grow0, int ct, int lane, f32x4* acc)
{
    const int r = lane & 15, q = lane >> 4;

    f16x8 xv[NR][NPS];
    #pragma unroll
    for (int nr = 0; nr < NR; ++nr) {
        const _Float16* xp = src0 + (size_t)(nr * 16 + r) * STRIDE + q * 8;
        #pragma unroll
        for (int j = 0; j < NPS; ++j) xv[nr][j] = *(const f16x8*)(xp + j * 32);
    }
    _Float16 ys[NR][H];
    if (SCALE) {
        #pragma unroll
        for (int nr = 0; nr < NR; ++nr)
            #pragma unroll
            for (int h = 0; h < H; ++h)
                ys[nr][h] = (h < 10) ? (_Float16)hx[(grow0 + nr * 16 + r) * 10 + h]
                                     : (_Float16)1.f;
    }
    f32x4 z = {0.f, 0.f, 0.f, 0.f};
    #pragma unroll
    for (int nr = 0; nr < NR; ++nr) acc[nr] = z;

    const _Float16* wbase = Wl + ((size_t)ct * 64 + lane) * 8;
    constexpr int TOT = H * NPS;
    constexpr int BS  = 8;
    constexpr int NB  = (TOT + BS - 1) / BS;

    f16x8 bf[2][BS];
    #pragma unroll
    for (int u = 0; u < BS; ++u)
        if (u < TOT)
            bf[0][u] = *(const f16x8*)(wbase + (size_t)(u * CT) * 512);

    #pragma unroll
    for (int b = 0; b < NB; ++b) {
        if (b + 1 < NB) {
            #pragma unroll
            for (int u = 0; u < BS; ++u) {
                const int t = (b + 1) * BS + u;
                if (t < TOT)
                    bf[(b + 1) & 1][u] = *(const f16x8*)(wbase + (size_t)(t * CT) * 512);
            }
        }
        #pragma unroll
        for (int u = 0; u < BS; ++u) {
            const int t = b * BS + u;
            if (t < TOT) {
                const int h = t / NPS, j = t - h * NPS;
                #pragma unroll
                for (int nr = 0; nr < NR; ++nr) {
                    f16x8 a = xv[nr][j];
                    if (SCALE) {
                        const _Float16 s = ys[nr][h];
                        f16x8 y8 = {s, s, s, s, s, s, s, s};
                        a = a * y8;
                    }
                    acc[nr] = __builtin_amdgcn_mfma_f32_16x16x32_f16(
                        a, bf[b & 1][u], acc[nr], 0, 0, 0);
                }
            }
        }
    }
}

// ---------------------------- mega kernel ----------------------------------

__global__ __launch_bounds__(NTHR) void mega_kernel(
    const float* __restrict__ hx,   const float* __restrict__ mlp_x,
    const float* __restrict__ G0w,  const float* __restrict__ G0b,
    const float* __restrict__ G1w,  const float* __restrict__ G1b,
    const float* __restrict__ Wmw0, const float* __restrict__ bmw0,
    const float* __restrict__ Wmb0, const float* __restrict__ bmb0,
    const float* __restrict__ Wmw1, const float* __restrict__ bmw1,
    const float* __restrict__ Wmb1, const float* __restrict__ bmb1,
    const float* __restrict__ Wmw2, const float* __restrict__ bmw2,
    const float* __restrict__ Wmb2, const float* __restrict__ bmb2,
    const float* __restrict__ Wmw3, const float* __restrict__ bmw3,
    const float* __restrict__ Wmb3, const float* __restrict__ bmb3,
    const float* __restrict__ Wew,  const float* __restrict__ bew,
    const float* __restrict__ Web,  const float* __restrict__ beb,
    const float* __restrict__ Wlw,  const float* __restrict__ blw,
    const float* __restrict__ Wlb,  const float* __restrict__ blb,
    char* __restrict__ ws, float* __restrict__ out)
{
    __shared__ __align__(16) _Float16 lds_e[32 * 104];   // P5 LE staging

    const int tid  = threadIdx.x;
    const int bid  = blockIdx.x;
    const int id   = bid * NTHR + tid;
    const int lane = tid & 63;
    const int w    = tid >> 6;
    const int gw   = bid * 8 + w;
    const int r = lane & 15, q = lane >> 4;

    _Float16* Wp  = (_Float16*)ws;
    _Float16* xa0 = (_Float16*)(ws + WS_XA0);
    _Float16* xg1 = (_Float16*)(ws + WS_XG1);
    _Float16* xl0 = (_Float16*)(ws + WS_XL0);
    _Float16* xl1 = (_Float16*)(ws + WS_XL1);
    _Float16* xl2 = (_Float16*)(ws + WS_XL2);
    _Float16* xa3 = (_Float16*)(ws + WS_XA3);
    int* bar = (int*)(ws + WS_BAR);

    // ---------------- P0: prep G1+L0 blobs + g0 + pad init -----------------
    if (id < CHUNKS_P0) {
        if (id < 9216)
            prep_layer<256,288,256,256, 1>(id,        nullptr, G1w, nullptr, G1b, Wp + OFF_G1);
        else
            prep_layer<256,288,128,128,11>(id - 9216, Wmw0, bmw0, Wmb0, bmb0, Wp + OFF_L0);
    }
    // g0 = relu(mlp_x @ G0w + G0b) -> xa0
    #pragma unroll
    for (int half = 0; half < 2; ++half) {
        const int row = (id >> 8) + half * 512;
        const int col = id & 255;
        float acc = G0b[col];
        #pragma unroll
        for (int n = 0; n < 9; ++n)
            acc = fmaf(mlp_x[row * 9 + n], G0w[n * 256 + col], acc);
        st_h(&xa0[(size_t)row * 288 + col], (_Float16)fmaxf(acc, 0.f));
    }
    // pad columns: slot M = 1.0 (augment), rest 0 (separate 64B lines)
    if (id < 32768) {
        const int rr = id >> 5, o = id & 31;
        const _Float16 v = (o == 0) ? (_Float16)1.f : (_Float16)0.f;
        st_h(&xa0[(size_t)rr * 288 + 256 + o], v);
        st_h(&xl0[(size_t)rr * 160 + 128 + o], v);
        st_h(&xl1[(size_t)rr * 160 + 128 + o], v);
        st_h(&xl2[(size_t)rr * 160 + 128 + o], v);
        st_h(&xa3[(size_t)rr * 288 + 256 + o], v);
    }
    grid_barrier(bar, 1);

    // ---------------- P1: L0 (blocks 0-63) || prep rest (64-255) -----------
    if (bid < 64) {
        const int ct = bid >> 3, rb = 8 * (bid & 7) + w;
        f32x4 acc[1];
        layer_waveN<1, 9, 11, 8, true, 288>(Wp + OFF_L0, xa0 + (size_t)rb * 16 * 288,
                                            hx, rb * 16, ct, lane, acc);
        #pragma unroll
        for (int t4 = 0; t4 < 4; ++t4)
            st_h(&xl0[(size_t)(rb * 16 + q * 4 + t4) * 160 + ct * 16 + r],
                 (_Float16)fmaxf(acc[0][t4], 0.f));
    } else {
        const int pid = (bid - 64) * NTHR + tid;  // 0..98303
        for (int ci = CHUNKS_P0 + pid; ci < TOTAL_CHUNKS; ci += 98304) {
            if (ci < 88064)
                prep_layer<128,160,128,128,11>(ci - 59904,  Wmw1, bmw1, Wmb1, bmb1, Wp + OFF_L1);
            else if (ci < 116224)
                prep_layer<128,160,128,128,11>(ci - 88064,  Wmw2, bmw2, Wmb2, bmb2, Wp + OFF_L2);
            else if (ci < 172544)
                prep_layer<128,160,256,256,11>(ci - 116224, Wmw3, bmw3, Wmb3, bmb3, Wp + OFF_L3);
            else if (ci < 197888)
                prep_layer<256,288, 64, 64,11>(ci - 172544, Wew,  bew,  Web,  beb,  Wp + OFF_LE);
            else
                prep_layer< 64, 96, 16,  8,11>(ci - 197888, Wlw,  blw,  Wlb,  blb,  Wp + OFF_LL);
        }
    }
    grid_barrier(bar, 2);

    // ---------------- P2: L1 (blocks 0-63) ----------------------------------
    if (bid < 64) {
        const int ct = bid >> 3, rb = 8 * (bid & 7) + w;
        f32x4 acc[1];
        layer_waveN<1, 5, 11, 8, true, 160>(Wp + OFF_L1, xl0 + (size_t)rb * 16 * 160,
                                            hx, rb * 16, ct, lane, acc);
        #pragma unroll
        for (int t4 = 0; t4 < 4; ++t4)
            st_h(&xl1[(size_t)(rb * 16 + q * 4 + t4) * 160 + ct * 16 + r],
                 (_Float16)fmaxf(acc[0][t4], 0.f));
    }
    grid_barrier(bar, 3);

    // ---------------- P3: L2 (blocks 0-63) || g1 (blocks 64-127) ------------
    if (bid < 64) {
        const int ct = bid >> 3, rb = 8 * (bid & 7) + w;
        f32x4 acc[1];
        layer_waveN<1, 5, 11, 8, true, 160>(Wp + OFF_L2, xl1 + (size_t)rb * 16 * 160,
                                            hx, rb * 16, ct, lane, acc);
        #pragma unroll
        for (int t4 = 0; t4 < 4; ++t4)
            st_h(&xl2[(size_t)(rb * 16 + q * 4 + t4) * 160 + ct * 16 + r],
                 (_Float16)fmaxf(acc[0][t4], 0.f));
    } else if (bid < 128) {
        const int t = (bid - 64) * 8 + w, ct = t >> 5, rbg = t & 31;
        f32x4 acc[2];
        layer_waveN<2, 9, 1, 16, false, 288>(Wp + OFF_G1, xa0 + (size_t)rbg * 32 * 288,
                                             hx, rbg * 32, ct, lane, acc);
        #pragma unroll
        for (int nr = 0; nr < 2; ++nr)
            #pragma unroll
            for (int t4 = 0; t4 < 4; ++t4)
                st_h(&xg1[(size_t)(rbg * 32 + nr * 16 + q * 4 + t4) * 256 + ct * 16 + r],
                     (_Float16)fmaxf(acc[nr][t4], 0.f));
    }
    grid_barrier(bar, 4);

    // ---------------- P4: L3 mask (blocks 0-63): sigmoid(.)*g1 -> xa3 -------
    if (bid < 64) {
        const int ct = gw >> 5, rbg = gw & 31;
        f32x4 acc[2];
        layer_waveN<2, 5, 11, 16, true, 160>(Wp + OFF_L3, xl2 + (size_t)rbg * 32 * 160,
                                             hx, rbg * 32, ct, lane, acc);
        #pragma unroll
        for (int nr = 0; nr < 2; ++nr)
            #pragma unroll
            for (int t4 = 0; t4 < 4; ++t4) {
                const int row = rbg * 32 + nr * 16 + q * 4 + t4;
                const int col = ct * 16 + r;
                float v = 1.f / (1.f + __expf(-acc[nr][t4]));
                v *= (float)xg1[(size_t)row * 256 + col];
                st_h(&xa3[(size_t)row * 288 + col], (_Float16)v);
            }
    }
    grid_barrier(bar, 5);

    // ---------------- P5: LE -> LDS -> LL -> out (blocks 0-31) --------------
    if (bid < 32) {
        {
            const int rbl = w >> 2, ct = w & 3;
            const int grow = (2 * bid + rbl) * 16;
            f32x4 acc[1];
            layer_waveN<1, 9, 11, 4, true, 288>(Wp + OFF_LE, xa3 + (size_t)grow * 288,
                                                hx, grow, ct, lane, acc);
            #pragma unroll
            for (int t4 = 0; t4 < 4; ++t4)
                lds_e[(rbl * 16 + q * 4 + t4) * 104 + ct * 16 + r] =
                    (_Float16)fmaxf(acc[0][t4], 0.f);
        }
        // pad cols 64..95 of all 32 LDS rows (aug 1.0 at 64)
        #pragma unroll
        for (int ii = 0; ii < 2; ++ii) {
            const int idx = tid + ii * 512;
            const int row = idx >> 5, o = idx & 31;
            lds_e[row * 104 + 64 + o] = (o == 0) ? (_Float16)1.f : (_Float16)0.f;
        }
        __syncthreads();
        if (w < 2) {
            const int grow = (2 * bid + w) * 16;
            f32x4 acc[1];
            layer_waveN<1, 3, 11, 1, true, 104>(Wp + OFF_LL, lds_e + w * 16 * 104,
                                                hx, grow, 0, lane, acc);
            if (r < 8) {
                #pragma unroll
                for (int t4 = 0; t4 < 4; ++t4)
                    out[(size_t)(grow + q * 4 + t4) * 8 + r] = acc[0][t4];
            }
        }
    }
}

// ---------------------------- launch ---------------------------------------

extern "C" void kernel_launch(void* const* d_in, const int* in_sizes, int n_in,
                              void* d_out, int out_size, void* d_ws, size_t ws_size,
                              hipStream_t stream)
{
    char* ws = (char*)d_ws;
    hipMemsetAsync(ws + WS_BAR, 0, 1280, stream);   // root + 16 group counters

    mega_kernel<<<NBLK, NTHR, 0, stream>>>(
        (const float*)d_in[0],  (const float*)d_in[1],
        (const float*)d_in[2],  (const float*)d_in[3],
        (const float*)d_in[4],  (const float*)d_in[5],
        (const float*)d_in[6],  (const float*)d_in[7],  (const float*)d_in[8],  (const float*)d_in[9],
        (const float*)d_in[10], (const float*)d_in[11], (const float*)d_in[12], (const float*)d_in[13],
        (const float*)d_in[14], (const float*)d_in[15], (const float*)d_in[16], (const float*)d_in[17],
        (const float*)d_in[18], (const float*)d_in[19], (const float*)d_in[20], (const float*)d_in[21],
        (const float*)d_in[22], (const float*)d_in[23], (const float*)d_in[24], (const float*)d_in[25],
        (const float*)d_in[26], (const float*)d_in[27], (const float*)d_in[28], (const float*)d_in[29],
        ws, (float*)d_out);
}

// Round 11
// 63.409 us; speedup vs baseline: 1.9867x; 1.0596x over previous
//
#include <hip/hip_runtime.h>
#include <math.h>

// ---------------------------------------------------------------------------
// HyperMTANPro fused hypernetwork-MLP, MI355X (gfx950) — round 11.
//
// Persistent mega-kernel, 256 blocks x 512 threads, manual grid barriers.
// Coherence recipe (r9, proven): cross-phase global stores = AGENT-scope
// relaxed atomic stores (sc1 write-through, MALL-acked; XCD L2s never dirty);
// barrier = all-relaxed tree (16 group ctrs 64B apart -> root; poll =
// relaxed agent load + s_sleep).
//
// r10 lesson: per-wave B streaming stays MALL-latency-bound (compiler
// collapses source-level pipelines; VGPR=68 proved it). r11: blob is packed
// CT-MAJOR (ct-slice contiguous); each block reg-stages its <=99KB slice
// into LDS once (512 threads x <=13 independent dwordx4 -> one latency),
// then waves read B via contiguous conflict-free ds_read_b128. Cross-phase
// prefetch fills the idle LDS region (L2 during P2; L3+LE during P3; LL
// during P5). LDS = 99+55 KB = 157696 B (1 block/CU).
//
// Schedule (A = ldsA 99KB, B = ldsB 55KB):
//   P0: prep G1+L0 blobs + g0 + pad cols                          | bar1
//   P1: [0-63] stage L0->A, compute L0      | [64-255] prep rest  | bar2
//   P2: [0-63] stage L1->B + L2->A, cmp L1  | [64-127] g1         | bar3
//   P3: [0-63] cmp L2 (A); stage L3->B, LE->A                     | bar4
//   P4: [0-63] cmp L3 (B) -> sigmoid*g1 -> xa3                    | bar5
//   P5: [0-63] stage LL->B; cmp LE (A, waves 0-3) -> xae          | bar6
//   P6: [0-7]  cmp LL (B) -> out
//
// Refold: pbmm(x, hx@Wh+bh) + (hx@Wb+bb)  ==  [y (x) xa] @ Wfold
//   y = [hyper_x, 1] (H=11), xa = [x, 1, 0-pad] (NP mult of 32), k = h*NP+n.
// Blob v2 layout (ct-major): layer base + ct*NS*512 halfs; frag t (=h*NPS+j)
// at +t*512; lane l owns halfs [t*512+l*8 .. +8) = W'[k=t*32+(l>>4)*8+i]
// [col=ct*16+(l&15)].
// ---------------------------------------------------------------------------

typedef _Float16 f16x8 __attribute__((ext_vector_type(8)));
typedef float    f32x4 __attribute__((ext_vector_type(4)));
typedef unsigned long long u64;

#define NBLK 256
#define NTHR 512
#define NTOT (NBLK * NTHR)

// blob half-offsets (layer sizes unchanged; intra-layer order is ct-major)
#define OFF_G1 0
#define OFF_L0 73728
#define OFF_L1 479232
#define OFF_L2 704512
#define OFF_L3 929792
#define OFF_LE 1380352
#define OFF_LL 1583104
#define TOTAL_CHUNKS 200000
#define CHUNKS_P0 59904        // G1 (9216) + L0 (50688)

// d_ws byte offsets
#define WS_XA0 3200000         // [1024][288] f16  g0 (+aug/pad)
#define WS_XG1 3789824         // [1024][256] f16  g1
#define WS_XL0 4314112         // [1024][160] f16  L0
#define WS_XL1 4641792         // [1024][160] f16  L1
#define WS_XL2 4969472         // [1024][160] f16  L2
#define WS_XA3 5297152         // [1024][288] f16  mask*g1
#define WS_XAE 5886976         // [1024][96]  f16  extractor
#define WS_BAR 6083584         // root int[16] + 16 group ctrs @64B

// ---- sc1 write-through store helpers --------------------------------------

__device__ __forceinline__ void st_h(_Float16* p, _Float16 v)
{
    unsigned short b = __builtin_bit_cast(unsigned short, v);
    __hip_atomic_store((unsigned short*)p, b, __ATOMIC_RELAXED,
                       __HIP_MEMORY_SCOPE_AGENT);
}

__device__ __forceinline__ void st_v8(_Float16* p, f16x8 v)
{
    union { f16x8 v; u64 u[2]; } cv; cv.v = v;
    u64* q = (u64*)p;
    __hip_atomic_store(q,     cv.u[0], __ATOMIC_RELAXED, __HIP_MEMORY_SCOPE_AGENT);
    __hip_atomic_store(q + 1, cv.u[1], __ATOMIC_RELAXED, __HIP_MEMORY_SCOPE_AGENT);
}

// ---------------------------- weight prep (ct-major) -----------------------

template<int N, int NP, int Mp, int M, int H>
__device__ __forceinline__ void prep_layer(int lci,
    const float* __restrict__ Wm, const float* __restrict__ bm,
    const float* __restrict__ Wb, const float* __restrict__ bb,
    _Float16* __restrict__ dst)
{
    constexpr int NS = (H * NP) / 32;     // frags per ct-slice
    const int l  = lci & 63;
    const int sc = lci >> 6;
    const int c  = sc / NS;               // ct (slice-major!)
    const int s  = sc - c * NS;
    const int col = c * 16 + (l & 15);
    const int k0  = s * 32 + ((l >> 4) << 3);
    const int h   = k0 / NP;
    const int n0  = k0 - h * NP;

    f16x8 v;
    #pragma unroll
    for (int i = 0; i < 8; ++i) {
        const int n = n0 + i;
        float w = 0.f;
        if (col < M && n <= N) {
            if (H == 11 && h < 10)
                w = (n < N) ? Wm[h * (N * M) + n * M + col] : Wb[h * M + col];
            else
                w = (n < N) ? bm[n * M + col] : bb[col];
        }
        v[i] = (_Float16)w;
    }
    st_v8(dst + (size_t)lci * 8, v);
}

// ---------------------------- grid barrier ---------------------------------

__device__ __forceinline__ void grid_barrier(int* barbase, int gen)
{
    __syncthreads();                 // drains vmcnt(0): sc1 stores MALL-acked
    if (threadIdx.x == 0) {
        int* root = barbase;
        int* grp  = barbase + 16 + ((blockIdx.x >> 4) << 4);
        const int old = __hip_atomic_fetch_add(grp, 1, __ATOMIC_RELAXED,
                                               __HIP_MEMORY_SCOPE_AGENT);
        if (old == gen * 16 - 1)
            __hip_atomic_fetch_add(root, 1, __ATOMIC_RELAXED,
                                   __HIP_MEMORY_SCOPE_AGENT);
        while (__hip_atomic_load(root, __ATOMIC_RELAXED,
                                 __HIP_MEMORY_SCOPE_AGENT) < gen * 16)
            __builtin_amdgcn_s_sleep(1);
    }
    __syncthreads();
}

// ---------------------------- slice staging --------------------------------
// Reg-staged: each thread loads its 16B chunks (all independent -> one
// latency), then ds_write_b128. Contiguous per wave on both sides.

template<int NFRAG16>
__device__ __forceinline__ void stage(const _Float16* __restrict__ g,
                                      _Float16* __restrict__ l, int tid)
{
    constexpr int ITER = (NFRAG16 + 511) / 512;
    f16x8 v[ITER];
    #pragma unroll
    for (int i = 0; i < ITER; ++i) {
        const int f = i * 512 + tid;
        if (f < NFRAG16) v[i] = *(const f16x8*)(g + (size_t)f * 8);
    }
    #pragma unroll
    for (int i = 0; i < ITER; ++i) {
        const int f = i * 512 + tid;
        if (f < NFRAG16) *(f16x8*)(l + (size_t)f * 8) = v[i];
    }
}

// ---------------------------- layer wave -----------------------------------
// Wf = slice base (LDS or global): frag t at Wf + t*512 + lane*8.

template<int NR, int NPS, int H, bool SCALE, int STRIDE>
__device__ __forceinline__ void layer_waveN(
    const _Float16* __restrict__ Wf,
    const _Float16* __restrict__ src0,   // activation rows (row 0 of tile)
    const float* __restrict__ hx,
    int grow0, int lane, f32x4* acc)
{
    const int r = lane & 15, q = lane >> 4;

    f16x8 xv[NR][NPS];
    #pragma unroll
    for (int nr = 0; nr < NR; ++nr) {
        const _Float16* xp = src0 + (size_t)(nr * 16 + r) * STRIDE + q * 8;
        #pragma unroll
        for (int j = 0; j < NPS; ++j) xv[nr][j] = *(const f16x8*)(xp + j * 32);
    }
    _Float16 ys[NR][H];
    if (SCALE) {
        #pragma unroll
        for (int nr = 0; nr < NR; ++nr)
            #pragma unroll
            for (int h = 0; h < H; ++h)
                ys[nr][h] = (h < 10) ? (_Float16)hx[(grow0 + nr * 16 + r) * 10 + h]
                                     : (_Float16)1.f;
    }
    f32x4 z = {0.f, 0.f, 0.f, 0.f};
    #pragma unroll
    for (int nr = 0; nr < NR; ++nr) acc[nr] = z;

    const _Float16* wl = Wf + lane * 8;
    #pragma unroll
    for (int h = 0; h < H; ++h) {
        #pragma unroll
        for (int j = 0; j < NPS; ++j) {
            f16x8 b = *(const f16x8*)(wl + (size_t)(h * NPS + j) * 512);
            #pragma unroll
            for (int nr = 0; nr < NR; ++nr) {
                f16x8 a = xv[nr][j];
                if (SCALE) {
                    const _Float16 s = ys[nr][h];
                    f16x8 y8 = {s, s, s, s, s, s, s, s};
                    a = a * y8;
                }
                acc[nr] = __builtin_amdgcn_mfma_f32_16x16x32_f16(a, b, acc[nr], 0, 0, 0);
            }
        }
    }
}

// ---------------------------- mega kernel ----------------------------------

__global__ __launch_bounds__(NTHR) void mega_kernel(
    const float* __restrict__ hx,   const float* __restrict__ mlp_x,
    const float* __restrict__ G0w,  const float* __restrict__ G0b,
    const float* __restrict__ G1w,  const float* __restrict__ G1b,
    const float* __restrict__ Wmw0, const float* __restrict__ bmw0,
    const float* __restrict__ Wmb0, const float* __restrict__ bmb0,
    const float* __restrict__ Wmw1, const float* __restrict__ bmw1,
    const float* __restrict__ Wmb1, const float* __restrict__ bmb1,
    const float* __restrict__ Wmw2, const float* __restrict__ bmw2,
    const float* __restrict__ Wmb2, const float* __restrict__ bmb2,
    const float* __restrict__ Wmw3, const float* __restrict__ bmw3,
    const float* __restrict__ Wmb3, const float* __restrict__ bmb3,
    const float* __restrict__ Wew,  const float* __restrict__ bew,
    const float* __restrict__ Web,  const float* __restrict__ beb,
    const float* __restrict__ Wlw,  const float* __restrict__ blw,
    const float* __restrict__ Wlb,  const float* __restrict__ blb,
    char* __restrict__ ws, float* __restrict__ out)
{
    __shared__ __align__(16) _Float16 ldsA[50688];   // 99 KB (L0/L2/LE slices)
    __shared__ __align__(16) _Float16 ldsB[28160];   // 55 KB (L1/L3/LL slices)

    const int tid  = threadIdx.x;
    const int bid  = blockIdx.x;
    const int id   = bid * NTHR + tid;
    const int lane = tid & 63;
    const int w    = tid >> 6;
    const int r = lane & 15, q = lane >> 4;

    _Float16* Wp  = (_Float16*)ws;
    _Float16* xa0 = (_Float16*)(ws + WS_XA0);
    _Float16* xg1 = (_Float16*)(ws + WS_XG1);
    _Float16* xl0 = (_Float16*)(ws + WS_XL0);
    _Float16* xl1 = (_Float16*)(ws + WS_XL1);
    _Float16* xl2 = (_Float16*)(ws + WS_XL2);
    _Float16* xa3 = (_Float16*)(ws + WS_XA3);
    _Float16* xae = (_Float16*)(ws + WS_XAE);
    int* bar = (int*)(ws + WS_BAR);

    // ---------------- P0: prep G1+L0 + g0 + pads ----------------------------
    if (id < CHUNKS_P0) {
        if (id < 9216)
            prep_layer<256,288,256,256, 1>(id,        nullptr, G1w, nullptr, G1b, Wp + OFF_G1);
        else
            prep_layer<256,288,128,128,11>(id - 9216, Wmw0, bmw0, Wmb0, bmb0, Wp + OFF_L0);
    }
    #pragma unroll
    for (int half = 0; half < 2; ++half) {
        const int row = (id >> 8) + half * 512;
        const int col = id & 255;
        float acc = G0b[col];
        #pragma unroll
        for (int n = 0; n < 9; ++n)
            acc = fmaf(mlp_x[row * 9 + n], G0w[n * 256 + col], acc);
        st_h(&xa0[(size_t)row * 288 + col], (_Float16)fmaxf(acc, 0.f));
    }
    if (id < 32768) {
        const int rr = id >> 5, o = id & 31;
        const _Float16 v = (o == 0) ? (_Float16)1.f : (_Float16)0.f;
        st_h(&xa0[(size_t)rr * 288 + 256 + o], v);
        st_h(&xl0[(size_t)rr * 160 + 128 + o], v);
        st_h(&xl1[(size_t)rr * 160 + 128 + o], v);
        st_h(&xl2[(size_t)rr * 160 + 128 + o], v);
        st_h(&xa3[(size_t)rr * 288 + 256 + o], v);
        st_h(&xae[(size_t)rr * 96  +  64 + o], v);
    }
    grid_barrier(bar, 1);

    // ---------------- P1: stage L0 + compute L0 || prep rest ----------------
    if (bid < 64) {
        stage<6336>(Wp + OFF_L0 + (size_t)(bid >> 3) * 99 * 512, ldsA, tid);
        __syncthreads();
        const int rb = 8 * (bid & 7) + w;
        const int ct = bid >> 3;
        f32x4 acc[1];
        layer_waveN<1, 9, 11, true, 288>(ldsA, xa0 + (size_t)rb * 16 * 288,
                                         hx, rb * 16, lane, acc);
        #pragma unroll
        for (int t4 = 0; t4 < 4; ++t4)
            st_h(&xl0[(size_t)(rb * 16 + q * 4 + t4) * 160 + ct * 16 + r],
                 (_Float16)fmaxf(acc[0][t4], 0.f));
    } else {
        const int pid = (bid - 64) * NTHR + tid;
        for (int ci = CHUNKS_P0 + pid; ci < TOTAL_CHUNKS; ci += 98304) {
            if (ci < 88064)
                prep_layer<128,160,128,128,11>(ci - 59904,  Wmw1, bmw1, Wmb1, bmb1, Wp + OFF_L1);
            else if (ci < 116224)
                prep_layer<128,160,128,128,11>(ci - 88064,  Wmw2, bmw2, Wmb2, bmb2, Wp + OFF_L2);
            else if (ci < 172544)
                prep_layer<128,160,256,256,11>(ci - 116224, Wmw3, bmw3, Wmb3, bmb3, Wp + OFF_L3);
            else if (ci < 197888)
                prep_layer<256,288, 64, 64,11>(ci - 172544, Wew,  bew,  Web,  beb,  Wp + OFF_LE);
            else
                prep_layer< 64, 96, 16,  8,11>(ci - 197888, Wlw,  blw,  Wlb,  blb,  Wp + OFF_LL);
        }
    }
    grid_barrier(bar, 2);

    // ---------------- P2: stage L1->B, L2->A, compute L1 || g1 --------------
    if (bid < 64) {
        stage<3520>(Wp + OFF_L1 + (size_t)(bid >> 3) * 55 * 512, ldsB, tid);
        stage<3520>(Wp + OFF_L2 + (size_t)(bid >> 3) * 55 * 512, ldsA, tid);
        __syncthreads();
        const int rb = 8 * (bid & 7) + w;
        const int ct = bid >> 3;
        f32x4 acc[1];
        layer_waveN<1, 5, 11, true, 160>(ldsB, xl0 + (size_t)rb * 16 * 160,
                                         hx, rb * 16, lane, acc);
        #pragma unroll
        for (int t4 = 0; t4 < 4; ++t4)
            st_h(&xl1[(size_t)(rb * 16 + q * 4 + t4) * 160 + ct * 16 + r],
                 (_Float16)fmaxf(acc[0][t4], 0.f));
    } else if (bid < 128) {
        const int t = (bid - 64) * 8 + w, ct = t >> 5, rbg = t & 31;
        f32x4 acc[2];
        layer_waveN<2, 9, 1, false, 288>(Wp + OFF_G1 + (size_t)ct * 9 * 512,
                                         xa0 + (size_t)rbg * 32 * 288,
                                         hx, rbg * 32, lane, acc);
        #pragma unroll
        for (int nr = 0; nr < 2; ++nr)
            #pragma unroll
            for (int t4 = 0; t4 < 4; ++t4)
                st_h(&xg1[(size_t)(rbg * 32 + nr * 16 + q * 4 + t4) * 256 + ct * 16 + r],
                     (_Float16)fmaxf(acc[nr][t4], 0.f));
    }
    grid_barrier(bar, 3);

    // ---------------- P3: compute L2 (A); prefetch L3->B, LE->A -------------
    if (bid < 64) {
        const int rb = 8 * (bid & 7) + w;
        const int ct = bid >> 3;
        f32x4 acc[1];
        layer_waveN<1, 5, 11, true, 160>(ldsA, xl1 + (size_t)rb * 16 * 160,
                                         hx, rb * 16, lane, acc);
        #pragma unroll
        for (int t4 = 0; t4 < 4; ++t4)
            st_h(&xl2[(size_t)(rb * 16 + q * 4 + t4) * 160 + ct * 16 + r],
                 (_Float16)fmaxf(acc[0][t4], 0.f));
        __syncthreads();   // all waves done reading A/B before re-staging
        stage<3520>(Wp + OFF_L3 + (size_t)(bid >> 2) * 55 * 512, ldsB, tid);
        stage<6336>(Wp + OFF_LE + (size_t)(bid >> 4) * 99 * 512, ldsA, tid);
    }
    grid_barrier(bar, 4);

    // ---------------- P4: compute L3 (B): sigmoid(.)*g1 -> xa3 --------------
    if (bid < 64) {
        const int gw = bid * 8 + w;
        const int ct = gw >> 5, rbg = gw & 31;
        f32x4 acc[2];
        layer_waveN<2, 5, 11, true, 160>(ldsB, xl2 + (size_t)rbg * 32 * 160,
                                         hx, rbg * 32, lane, acc);
        #pragma unroll
        for (int nr = 0; nr < 2; ++nr)
            #pragma unroll
            for (int t4 = 0; t4 < 4; ++t4) {
                const int row = rbg * 32 + nr * 16 + q * 4 + t4;
                const int col = ct * 16 + r;
                float v = 1.f / (1.f + __expf(-acc[nr][t4]));
                v *= (float)xg1[(size_t)row * 256 + col];
                st_h(&xa3[(size_t)row * 288 + col], (_Float16)v);
            }
    }
    grid_barrier(bar, 5);

    // ---------------- P5: stage LL->B; compute LE (A, waves 0-3) -> xae -----
    if (bid < 64) {
        stage<2112>(Wp + OFF_LL, ldsB, tid);
        __syncthreads();
        if (w < 4) {
            const int rb = 4 * (bid & 15) + w;
            f32x4 acc[1];
            layer_waveN<1, 9, 11, true, 288>(ldsA, xa3 + (size_t)rb * 16 * 288,
                                             hx, rb * 16, lane, acc);
            const int ct = bid >> 4;
            #pragma unroll
            for (int t4 = 0; t4 < 4; ++t4)
                st_h(&xae[(size_t)(rb * 16 + q * 4 + t4) * 96 + ct * 16 + r],
                     (_Float16)fmaxf(acc[0][t4], 0.f));
        }
    }
    grid_barrier(bar, 6);

    // ---------------- P6: compute LL (B) -> out f32 -------------------------
    if (bid < 8) {
        const int rb = 8 * bid + w;
        f32x4 acc[1];
        layer_waveN<1, 3, 11, true, 96>(ldsB, xae + (size_t)rb * 16 * 96,
                                        hx, rb * 16, lane, acc);
        if (r < 8) {
            #pragma unroll
            for (int t4 = 0; t4 < 4; ++t4)
                out[(size_t)(rb * 16 + q * 4 + t4) * 8 + r] = acc[0][t4];
        }
    }
}

// ---------------------------- launch ---------------------------------------

extern "C" void kernel_launch(void* const* d_in, const int* in_sizes, int n_in,
                              void* d_out, int out_size, void* d_ws, size_t ws_size,
                              hipStream_t stream)
{
    char* ws = (char*)d_ws;
    hipMemsetAsync(ws + WS_BAR, 0, 1280, stream);   // root + 16 group counters

    mega_kernel<<<NBLK, NTHR, 0, stream>>>(
        (const float*)d_in[0],  (const float*)d_in[1],
        (const float*)d_in[2],  (const float*)d_in[3],
        (const float*)d_in[4],  (const float*)d_in[5],
        (const float*)d_in[6],  (const float*)d_in[7],  (const float*)d_in[8],  (const float*)d_in[9],
        (const float*)d_in[10], (const float*)d_in[11], (const float*)d_in[12], (const float*)d_in[13],
        (const float*)d_in[14], (const float*)d_in[15], (const float*)d_in[16], (const float*)d_in[17],
        (const float*)d_in[18], (const float*)d_in[19], (const float*)d_in[20], (const float*)d_in[21],
        (const float*)d_in[22], (const float*)d_in[23], (const float*)d_in[24], (const float*)d_in[25],
        (const float*)d_in[26], (const float*)d_in[27], (const float*)d_in[28], (const float*)d_in[29],
        ws, (float*)d_out);
}